// Round 12
// baseline (295.704 us; speedup 1.0000x reference)
//
#include <hip/hip_runtime.h>
#include <math.h>

// SGRUCell T=32 B=8 I=512 H=512, all f32.
// Persistent kernel, 256 blocks x 1024 threads (1 block/CU -- the only
// residency-safe geometry: 512-block variants deadlock whenever VGPR>32
// because 2x16 waves x 64 VGPR needs the ENTIRE register file; rounds 10/11
// hung there). Block (q=blk>>3, b=blk&7) owns rows i in [16q,16q+16) of
// batch b; 16 waves, one full row per wave.
//
// Register budget (allocator pins 1024-thread kernels at 64 VGPRs; launch
// bounds cannot raise it -- measured rounds 4-9): persistent tables cut to
// 48 regs (wz,wdv,D=alpha*dU,al,upS,loS). tE state lives in LDS (32 KB);
// modU_w/modU_b are re-read from global each step (L2-resident, overlapped).
// => no spill (round 6 spilled ~7 floats: WRITE 24.9 vs 17.4 MB ideal).
//
// Barriers per step cut 5 -> 3: gates computed redundantly by every wave
// (no gates barrier / LDS round-trip); te_n computed on the fly inside the
// update loop (no te-pass barrier), single writeback pass after B3.
//
// Cross-block sync (proven rounds 6/9): producers atomic-store h bits into
// o_outs per-step slots (relaxed agent), s_waitcnt drain, B3, tid0 stores
// flag = t+1 into per-(b,q) slot; consumers poll the 32 batch flags with one
// wave, signed >= t (0xAAAAAAAA ws-poison is negative => no clearing pass;
// monotonic => no ABA). No fences anywhere.

__device__ __forceinline__ float wred(float v) {
#pragma unroll
  for (int o = 32; o > 0; o >>= 1) v += __shfl_xor(v, o, 64);
  return v;
}
__device__ __forceinline__ float sigm(float x) { return 1.f / (1.f + __expf(-x)); }

__global__ void prenorm_kernel(const float* __restrict__ xv, const float* __restrict__ xg,
                               const float* __restrict__ hv, const float* __restrict__ hg,
                               float* __restrict__ scx, float* __restrict__ sch) {
  int r = blockIdx.x, L = threadIdx.x;
  const float* vrow; const float* g; float* o; int rr;
  if (r < 1536) { rr = r; vrow = xv + (size_t)r * 512; g = xg; o = scx; }
  else { rr = r - 1536; vrow = hv + (size_t)rr * 512; g = hg; o = sch; }
  float s = 0.f;
#pragma unroll
  for (int m = 0; m < 8; m++) { float v = vrow[m * 64 + L]; s = fmaf(v, v, s); }
  s = wred(s);
  if (L == 0) o[rr] = g[rr] / sqrtf(s);
}

__global__ __launch_bounds__(1024, 4) void persist_kernel(
    const float* __restrict__ x,
    const float* __restrict__ h0, const float* __restrict__ v0,
    const float* __restrict__ dU0, const float* __restrict__ te0,
    const float* __restrict__ tE0,
    const float* __restrict__ x2h_v, const float* __restrict__ x2h_b,
    const float* __restrict__ h2h_v, const float* __restrict__ h2h_b,
    const float* __restrict__ alpha,
    const float* __restrict__ h2mod_w, const float* __restrict__ h2mod_b,
    const float* __restrict__ modU_w, const float* __restrict__ modU_b,
    const float* __restrict__ scx, const float* __restrict__ sch,
    int* __restrict__ flg,
    float* __restrict__ o_v, float* __restrict__ o_h,
    float* __restrict__ o_dU, float* __restrict__ o_te,
    float* __restrict__ o_tE, float* __restrict__ o_outs) {
  __shared__ float sh_h[2][512];      // h ping-pong: sh_h[t&1] = h_t
  __shared__ float sh_te[512];        // eligibility trace (te_{t-1} during step t)
  __shared__ float sh_tE[16][512];    // tE state, row-per-wave (32 KB)
  __shared__ float sh_mod[2048];      // h2mod_w (4x512)
  __shared__ float sh_xpz[32][16];    // x-proj (z) + biases, [t][wave/row]
  __shared__ float sh_xpdv[32][16];   // x-proj (dv) + biases

  const int tid = threadIdx.x;
  const int w = tid >> 6, L = tid & 63;
  const int b = blockIdx.x & 7, q = blockIdx.x >> 3;  // q in [0,32)
  const int i = q * 16 + w;  // owned row

  // ---- LDS staging ----
  if (tid < 512) {
    sh_h[0][tid] = h0[b * 512 + tid];
    sh_te[tid] = te0[b * 512 + tid];
  }
  sh_mod[tid] = h2mod_w[tid];
  sh_mod[tid + 1024] = h2mod_w[tid + 1024];

  const size_t row  = ((size_t)(b * 512 + i)) * 512;
  const size_t wrow = (size_t)i * 512;
  const float* hz_row  = h2h_v + (size_t)i * 512;
  const float* hr_row  = h2h_v + (size_t)(512 + i) * 512;
  const float* hdv_row = h2h_v + (size_t)(1024 + i) * 512;
  const float* xz_row  = x2h_v + (size_t)i * 512;
  const float* xdv_row = x2h_v + (size_t)(1024 + i) * 512;
  const float s_z = sch[i], s_r = sch[512 + i], s_dv = sch[1024 + i];
  const float sx_z = scx[i], sx_dv = scx[1024 + i];
  const float gb0 = h2mod_b[0], gb1 = h2mod_b[1];
  const float gb2 = h2mod_b[2], gb3 = h2mod_b[3];

  // ---- x-projection precompute (h-independent, all 32 steps) ----
  {
    float xz[8], xdv[8];
#pragma unroll
    for (int m = 0; m < 8; m++) {
      int c = m * 64 + L;
      xz[m]  = sx_z  * xz_row[c];
      xdv[m] = sx_dv * xdv_row[c];
    }
    float bz = 0.f, bdv = 0.f;
    if (L == 0) {
      bz  = x2h_b[i] + h2h_b[i];
      bdv = x2h_b[1024 + i] + h2h_b[1024 + i];
    }
#pragma unroll 4
    for (int t = 0; t < 32; t++) {
      const float* xr = x + (size_t)t * 4096 + b * 512;
      float a = 0.f, d = 0.f;
#pragma unroll
      for (int m = 0; m < 8; m++) {
        int c = m * 64 + L;
        float xv_ = xr[c];
        a = fmaf(xz[m], xv_, a);
        d = fmaf(xdv[m], xv_, d);
      }
      a = wred(a); d = wred(d);
      if (L == 0) { sh_xpz[t][w] = a + bz; sh_xpdv[t][w] = d + bdv; }
    }
  }

  // ---- persistent register tables: 6 arrays x8 = 48 regs (no spill) ----
  float wz[8], wdv[8], al[8], upS[8], loS[8], D[8];
#pragma unroll
  for (int m = 0; m < 8; m++) {
    int c = m * 64 + L;
    wz[m]  = s_z  * hz_row[c];
    wdv[m] = s_dv * hdv_row[c];
    float alv = alpha[wrow + c];
    al[m] = alv;
    float wrv = s_r * hr_row[c];
    float t1 = alv / (alv + 1e-5f);     // alpha-prescaled clip factor
    upS[m] = fmaxf(1.f - wrv, 0.f) * t1;
    loS[m] = -fmaxf(1.f + wrv, 0.f) * t1;
    D[m]  = alv * dU0[row + c];         // scaled state: D = alpha*dU
    sh_tE[w][c] = tE0[row + c];         // tE state in LDS
  }
  float v_reg = 0.f, hn_last = 0.f;
  if (L == 0) v_reg = v0[b * 512 + i];
  __syncthreads();

  unsigned* hxu = (unsigned*)o_outs;  // h exchanged through the output buffer

  for (int t = 0; t <= 32; t++) {
    const int cur = t & 1, prev = cur ^ 1;
    float taue = 0.f;
    if (t > 0) {
      // ---- B1: one wave polls the 32 batch flags (signed >= t) ----
      if (w == 0) {
        const int* fp = flg + b * 32 + (L & 31);
        int u = __hip_atomic_load(fp, __ATOMIC_RELAXED, __HIP_MEMORY_SCOPE_AGENT);
        while (!__all(u >= t)) {
          u = __hip_atomic_load(fp, __ATOMIC_RELAXED, __HIP_MEMORY_SCOPE_AGENT);
        }
      }
      __syncthreads();  // B1
      if (tid < 512) {  // one-shot read of h_t
        unsigned u = __hip_atomic_load(hxu + (size_t)(t - 1) * 4096 + b * 512 + tid,
                                       __ATOMIC_RELAXED, __HIP_MEMORY_SCOPE_AGENT);
        sh_h[cur][tid] = __uint_as_float(u);
      }
      __syncthreads();  // B2
      // gates: computed redundantly by EVERY wave (no barrier, no LDS trip)
      float g0 = 0.f, g1 = 0.f, g2 = 0.f, g3 = 0.f;
#pragma unroll
      for (int m = 0; m < 8; m++) {
        int c = m * 64 + L;
        float hv_ = sh_h[cur][c];
        g0 = fmaf(hv_, sh_mod[c], g0);
        g1 = fmaf(hv_, sh_mod[512 + c], g1);
        g2 = fmaf(hv_, sh_mod[1024 + c], g2);
        g3 = fmaf(hv_, sh_mod[1536 + c], g3);
      }
      g0 = wred(g0); g1 = wred(g1); g2 = wred(g2); g3 = wred(g3);
      taue = sigm(g0 + gb0);
      float tauE = sigm(g1 + gb1);
      float tauU = sigm(g2 + gb2);
      float mU = fmaxf(g3 + gb3, 0.f);
      // update owned row: te on the fly, tE in LDS (own slots), D in regs
      float hn_i = sh_h[cur][i];
      float teo_i = sh_te[i];
      float te_i = fmaf(taue, sh_h[prev][i] - teo_i, teo_i);
#pragma unroll
      for (int m = 0; m < 8; m++) {
        int j = m * 64 + L;
        float teo_j = sh_te[j];
        float te_j = fmaf(taue, sh_h[prev][j] - teo_j, teo_j);
        float outer = hn_i * te_j - te_i * sh_h[cur][j];
        float tEo = sh_tE[w][j];
        float tEn = tEo + tauE * (outer - tEo);
        float a = fmaf(mU, modU_w[wrow + j], modU_b[wrow + j]);
        float sshr = (a > 0.5f) ? (a - 0.5f) : ((a < -0.5f) ? (a + 0.5f) : 0.f);
        float Dn = D[m] + tauU * (sshr * (al[m] * tEn) - D[m]);
        D[m] = fminf(fmaxf(Dn, loS[m]), upS[m]);
        sh_tE[w][j] = tEn;
      }
    }

    if (t < 32) {
      // z/dv row dots for step t (x-part precomputed; D = alpha*dU)
      float p1 = 0.f, p2 = 0.f;
#pragma unroll
      for (int m = 0; m < 8; m++) {
        int c = m * 64 + L;
        float hc = sh_h[cur][c];
        p1 = fmaf(wz[m], hc, p1);
        p2 = fmaf(wdv[m] + D[m], hc, p2);
      }
      p1 = wred(p1); p2 = wred(p2);
      if (L == 0) {
        float z = sigm(p1 + sh_xpz[t][w]);
        float dv = p2 + sh_xpdv[t][w];
        v_reg += z * (dv - v_reg);
        hn_last = fmaxf(v_reg, 0.f);
        __hip_atomic_store(hxu + (size_t)t * 4096 + b * 512 + i,
                           __float_as_uint(hn_last),
                           __ATOMIC_RELAXED, __HIP_MEMORY_SCOPE_AGENT);
      }
    }
    __builtin_amdgcn_s_waitcnt(0);  // drain h store (per-wave) before B3
    __syncthreads();                // B3
    if (t > 0 && tid < 512) {       // te writeback (safe: next read after B2 of t+1)
      float teo = sh_te[tid];
      sh_te[tid] = fmaf(taue, sh_h[prev][tid] - teo, teo);
    }
    if (t < 32 && tid == 0)
      __hip_atomic_store(flg + b * 32 + q, t + 1,
                         __ATOMIC_RELAXED, __HIP_MEMORY_SCOPE_AGENT);
  }
  __syncthreads();

  // ---- final writes ----
#pragma unroll
  for (int m = 0; m < 8; m++) {
    int c = m * 64 + L;
    float alv = al[m];
    o_dU[row + c] = (alv != 0.f) ? D[m] * __builtin_amdgcn_rcpf(alv) : 0.f;
    o_tE[row + c] = sh_tE[w][c];
  }
  if (L == 0) {
    o_v[b * 512 + i] = v_reg;
    o_h[b * 512 + i] = hn_last;
  }
  if (q == 0 && tid < 512) o_te[b * 512 + tid] = sh_te[tid];
}

extern "C" void kernel_launch(void* const* d_in, const int* in_sizes, int n_in,
                              void* d_out, int out_size, void* d_ws, size_t ws_size,
                              hipStream_t stream) {
  const float* x       = (const float*)d_in[0];
  const float* h0      = (const float*)d_in[1];
  const float* v0      = (const float*)d_in[2];
  const float* dU0     = (const float*)d_in[3];
  const float* te0     = (const float*)d_in[4];
  const float* tE0     = (const float*)d_in[5];
  const float* x2h_v   = (const float*)d_in[6];
  const float* x2h_g   = (const float*)d_in[7];
  const float* x2h_b   = (const float*)d_in[8];
  const float* h2h_v   = (const float*)d_in[9];
  const float* h2h_g   = (const float*)d_in[10];
  const float* h2h_b   = (const float*)d_in[11];
  const float* alpha   = (const float*)d_in[12];
  const float* h2mod_w = (const float*)d_in[13];
  const float* h2mod_b = (const float*)d_in[14];
  const float* modU_w  = (const float*)d_in[15];
  const float* modU_b  = (const float*)d_in[16];

  float* out = (float*)d_out;
  // output layout: v(4096) h(4096) dU(2097152) te(4096) tE(2097152) outs(131072)
  float* o_v    = out;
  float* o_h    = out + 4096;
  float* o_dU   = out + 8192;
  float* o_te   = out + 2105344;
  float* o_tE   = out + 2109440;
  float* o_outs = out + 4206592;

  int* flg = (int*)d_ws;      // 8 batches x 32 block-flags (1 KB); 0xAA poison
                              // is negative, flags monotonic t+1 => no clearing
  float* wsf = (float*)d_ws;
  float* scx = wsf + 512;     // 1536
  float* sch = wsf + 2048;    // 1536

  prenorm_kernel<<<dim3(3072), dim3(64), 0, stream>>>(x2h_v, x2h_g, h2h_v, h2h_g,
                                                      scx, sch);

  persist_kernel<<<dim3(256), dim3(1024), 0, stream>>>(
      x, h0, v0, dU0, te0, tE0, x2h_v, x2h_b, h2h_v, h2h_b, alpha,
      h2mod_w, h2mod_b, modU_w, modU_b, scx, sch, flg,
      o_v, o_h, o_dU, o_te, o_tE, o_outs);
}